// Round 16
// baseline (63.288 us; speedup 1.0000x reference)
//
#include <hip/hip_runtime.h>

#define R_    116
#define DIN_  116
#define H_    256

typedef float  f32x4   __attribute__((ext_vector_type(4)));
typedef float  f32x16  __attribute__((ext_vector_type(16)));
typedef short  short8  __attribute__((ext_vector_type(8)));
typedef int    int4v   __attribute__((ext_vector_type(4)));
typedef int    int2v   __attribute__((ext_vector_type(2)));

// ---- LDS layout (bytes). 16B-block XOR swizzle per row (block ^= row&7).
#define M_OFF    0        // M  [128 c][128 r] bf16 pitch 256B : bb=(r>>3)^(c&7); relu(m^T)+I
#define X_OFF    32768    // X  [128 r][128 k] bf16 pitch 256B : bb=(k>>3)^(r&7); zero-padded
#define H1_OFF   65536    // H1 [128 c][256 f] bf16 pitch 512B : bb=(f>>3)^(c&7); rows>=116 zeroed
#define DINV_OFF 131072   // 128 f32 (persistent)
#define RED_OFF  131584   // 16 f32
#define LDS_SIZE 131712

#define Z16 {0.f,0.f,0.f,0.f,0.f,0.f,0.f,0.f,0.f,0.f,0.f,0.f,0.f,0.f,0.f,0.f}

__device__ __forceinline__ short f2bf(float f) {
  union { float f; unsigned u; } x; x.f = f;
  unsigned r = x.u + 0x7fffu + ((x.u >> 16) & 1u);
  return (short)(r >> 16);
}
__device__ __forceinline__ float bf2f(short s) {
  union { unsigned u; float f; } x;
  x.u = ((unsigned)(unsigned short)s) << 16;
  return x.f;
}
// HW packed f32->bf16 RTNE: identical values to f2bf, 1 instruction per pair.
__device__ __forceinline__ unsigned pack2(float lo, float hi) {
  unsigned r;
  asm("v_cvt_pk_bf16_f32 %0, %1, %2" : "=v"(r) : "v"(lo), "v"(hi));
  return r;
}
__device__ __forceinline__ short8 mk8(unsigned a, unsigned b, unsigned c, unsigned d) {
  int4v t; t[0] = (int)a; t[1] = (int)b; t[2] = (int)c; t[3] = (int)d;
  return __builtin_bit_cast(short8, t);
}

// Pre-transpose weights to bf16 Wt[f][k], zero-padded K (layer 1).
__global__ void __launch_bounds__(256) wt_setup(const float* __restrict__ W1,
                                                const float* __restrict__ W2,
                                                short* __restrict__ W1t,
                                                short* __restrict__ W2t) {
  int idx = blockIdx.x * 256 + threadIdx.x;      // 384 blocks
  if (idx < 32768) {                             // W1t [256][128]
    int f = idx >> 7, k = idx & 127;
    float v = (k < DIN_) ? W1[k * H_ + f] : 0.f;
    W1t[idx] = f2bf(v);
  } else {                                       // W2t [256][256]
    int j = idx - 32768;
    int f = j >> 8, k = j & 255;
    W2t[j] = f2bf(W2[k * H_ + f]);
  }
}

// 8 waves (512 thr), 32x32x16 MFMA. Wave w owns f-tile w*32..w*32+31 for BOTH layers.
// ONE-PASS prologue: M filled c-major (half-wave owns a full padded M row ->
// conflict-free 8B stores, integrated deg via half-wave shfl reduce -> dinv),
// X filled over the padded space (no separate zero pass), H1 pad rows zeroed.
// Main loops identical to r12/r15 (in-register shfl transpose, no intra-layer barriers).
__global__ void __launch_bounds__(512, 2) gnn_fused(
    const float* __restrict__ mM, const float* __restrict__ nf,
    const float* __restrict__ b1, const float* __restrict__ b2,
    const float* __restrict__ Wc, const float* __restrict__ bc,
    const short* __restrict__ W1t, const short* __restrict__ W2t,
    float* __restrict__ out)
{
  extern __shared__ char smem[];
  const int b    = blockIdx.x;
  const int tid  = threadIdx.x;
  const int lane = tid & 63;
  const int w    = tid >> 6;     // 0..7 : f-tile (32 cols, both layers)
  const int n32  = lane & 31;
  const int hi   = lane >> 5;
  const int s7   = n32 & 7;

  // ---- fused prologue: M(+deg/dinv) + X + H1-pad, single pass, no pre-zero ----
  {
    const float* mB = mM + (size_t)b * (R_ * R_);
    const float* xB = nf + (size_t)b * (R_ * DIN_);
    float* dp = (float*)(smem + DINV_OFF);
#pragma unroll
    for (int it = 0; it < 8; ++it) {
      const int u = tid + it * 512;      // 4096 8B-units each for X and M
      // X [r][k] padded: unit (r, k0); half-wave = one full padded row
      {
        int r = u >> 5, k0 = (u & 31) * 4;
        f32x4 x4 = (f32x4){0.f, 0.f, 0.f, 0.f};
        if (r < R_ && k0 < DIN_) x4 = *(const f32x4*)(xB + r * DIN_ + k0);
        int2v px;
        px[0] = (int)pack2(x4[0], x4[1]);
        px[1] = (int)pack2(x4[2], x4[3]);
        int bx = (k0 >> 3) ^ (r & 7);
        *(int2v*)(smem + X_OFF + r * 256 + bx * 16 + (k0 & 7) * 2) = px;
      }
      // M [c][r] padded: unit (c, r0); value = relu(m[r][c]) + (r==c); deg integrated
      {
        int c = u >> 5, r0 = (u & 31) * 4;
        float v0 = 0.f, v1 = 0.f, v2 = 0.f, v3 = 0.f;
        if (c < R_ && r0 < R_) {         // 116%4==0 -> all-or-nothing per unit
          float t0 = mB[(r0 + 0) * R_ + c]; t0 = t0 > 0.f ? t0 : 0.f;
          float t1 = mB[(r0 + 1) * R_ + c]; t1 = t1 > 0.f ? t1 : 0.f;
          float t2 = mB[(r0 + 2) * R_ + c]; t2 = t2 > 0.f ? t2 : 0.f;
          float t3 = mB[(r0 + 3) * R_ + c]; t3 = t3 > 0.f ? t3 : 0.f;
          v0 = t0 + (r0 + 0 == c ? 1.f : 0.f);
          v1 = t1 + (r0 + 1 == c ? 1.f : 0.f);
          v2 = t2 + (r0 + 2 == c ? 1.f : 0.f);
          v3 = t3 + (r0 + 3 == c ? 1.f : 0.f);
        }
        // deg[c] = sum over all r (pads contribute 0); half-wave owns full column
        float s = v0 + v1 + v2 + v3;
        s += __shfl_xor(s, 1);
        s += __shfl_xor(s, 2);
        s += __shfl_xor(s, 4);
        s += __shfl_xor(s, 8);
        s += __shfl_xor(s, 16);
        if ((tid & 31) == 0) dp[c] = (c < R_) ? rsqrtf(s) : 0.f;
        int2v pm;
        pm[0] = (int)pack2(v0, v1);
        pm[1] = (int)pack2(v2, v3);
        int bm = (r0 >> 3) ^ (c & 7);
        *(int2v*)(smem + M_OFF + c * 256 + bm * 16 + (r0 & 7) * 2) = pm;
      }
    }
    // H1 pad rows 116..127 (6144B contiguous)
    if (tid < 384)
      ((int4v*)(smem + H1_OFF + 116 * 512))[tid] = (int4v){0, 0, 0, 0};
  }
  __syncthreads();

  const float* dinvp = (const float*)(smem + DINV_OFF);
  float dvc[4];
#pragma unroll
  for (int ct = 0; ct < 4; ++ct) dvc[ct] = dinvp[ct * 32 + n32];

  float ps0 = 0.f, ps1 = 0.f;

  // ================= Layer 1 (no internal barriers) =================
  {
    short8 w1f[8];
#pragma unroll
    for (int ks = 0; ks < 8; ++ks)
      w1f[ks] = *(const short8*)(W1t + (size_t)(w * 32 + n32) * 128 + ks * 16 + hi * 8);

    f32x16 acc2[4];
#pragma unroll
    for (int ct = 0; ct < 4; ++ct) acc2[ct] = (f32x16)Z16;

#pragma unroll
    for (int rb = 0; rb < 4; ++rb) {
      // phase A: xw tile [32 r x 32 f], D[r-quads][f=n32]
      f32x16 acc = (f32x16)Z16;
#pragma unroll
      for (int ks = 0; ks < 8; ++ks) {
        short8 xa = *(const short8*)(smem + X_OFF + (rb * 32 + n32) * 256 +
                                     (((ks * 2 + hi) ^ s7)) * 16);
        acc = __builtin_amdgcn_mfma_f32_32x32x16_bf16(xa, w1f[ks], acc, 0, 0, 0);
      }
      // in-register: scale by dinv[r], pack bf16, exchange lane^32 -> A-frags
      f32x4 dv0 = *(const f32x4*)(dinvp + rb * 32 + 0 + hi * 4);
      f32x4 dv1 = *(const f32x4*)(dinvp + rb * 32 + 8 + hi * 4);
      f32x4 dv2 = *(const f32x4*)(dinvp + rb * 32 + 16 + hi * 4);
      f32x4 dv3 = *(const f32x4*)(dinvp + rb * 32 + 24 + hi * 4);
      unsigned pk0l = pack2(acc[0] * dv0[0],  acc[1] * dv0[1]);
      unsigned pk0h = pack2(acc[2] * dv0[2],  acc[3] * dv0[3]);
      unsigned pk1l = pack2(acc[4] * dv1[0],  acc[5] * dv1[1]);
      unsigned pk1h = pack2(acc[6] * dv1[2],  acc[7] * dv1[3]);
      unsigned pk2l = pack2(acc[8] * dv2[0],  acc[9] * dv2[1]);
      unsigned pk2h = pack2(acc[10] * dv2[2], acc[11] * dv2[3]);
      unsigned pk3l = pack2(acc[12] * dv3[0], acc[13] * dv3[1]);
      unsigned pk3h = pack2(acc[14] * dv3[2], acc[15] * dv3[3]);
      unsigned rv0l = (unsigned)__shfl_xor((int)pk0l, 32);
      unsigned rv0h = (unsigned)__shfl_xor((int)pk0h, 32);
      unsigned rv1l = (unsigned)__shfl_xor((int)pk1l, 32);
      unsigned rv1h = (unsigned)__shfl_xor((int)pk1h, 32);
      unsigned rv2l = (unsigned)__shfl_xor((int)pk2l, 32);
      unsigned rv2h = (unsigned)__shfl_xor((int)pk2h, 32);
      unsigned rv3l = (unsigned)__shfl_xor((int)pk3l, 32);
      unsigned rv3h = (unsigned)__shfl_xor((int)pk3h, 32);
      short8 A0 = mk8(hi ? rv1l : pk0l, hi ? rv1h : pk0h,
                      hi ? pk1l : rv0l, hi ? pk1h : rv0h);
      short8 A1 = mk8(hi ? rv3l : pk2l, hi ? rv3h : pk2h,
                      hi ? pk3l : rv2l, hi ? pk3h : rv2h);
      // phase B: D2[f-quads][c=n32] += xs @ M^T (K = this rb's 32 r)
#pragma unroll
      for (int ct = 0; ct < 4; ++ct) {
        int c = ct * 32 + n32;
        short8 B0 = *(const short8*)(smem + M_OFF + c * 256 + ((rb * 4 + hi) ^ s7) * 16);
        short8 B1 = *(const short8*)(smem + M_OFF + c * 256 + ((rb * 4 + 2 + hi) ^ s7) * 16);
        acc2[ct] = __builtin_amdgcn_mfma_f32_32x32x16_bf16(A0, B0, acc2[ct], 0, 0, 0);
        acc2[ct] = __builtin_amdgcn_mfma_f32_32x32x16_bf16(A1, B1, acc2[ct], 0, 0, 0);
      }
    }

    // epilogue: h1 = leaky(dinv[c]*agg + b1[f]) -> H1[c][f]
    f32x4 bv[4];
#pragma unroll
    for (int rq = 0; rq < 4; ++rq)
      bv[rq] = *(const f32x4*)(b1 + w * 32 + rq * 8 + hi * 4);
#pragma unroll
    for (int ct = 0; ct < 4; ++ct) {
      int c = ct * 32 + n32;
      if (c < R_) {
        float dv = dvc[ct];
#pragma unroll
        for (int rq = 0; rq < 4; ++rq) {
          const int f0 = w * 32 + rq * 8 + hi * 4;
          float h0 = dv * acc2[ct][rq * 4 + 0] + bv[rq][0]; h0 = h0 > 0.f ? h0 : 0.2f * h0;
          float h1 = dv * acc2[ct][rq * 4 + 1] + bv[rq][1]; h1 = h1 > 0.f ? h1 : 0.2f * h1;
          float h2 = dv * acc2[ct][rq * 4 + 2] + bv[rq][2]; h2 = h2 > 0.f ? h2 : 0.2f * h2;
          float h3 = dv * acc2[ct][rq * 4 + 3] + bv[rq][3]; h3 = h3 > 0.f ? h3 : 0.2f * h3;
          int bb = (w * 4 + rq) ^ s7;            // (f0>>3)^(c&7), c&7==s7
          int2v pk;
          pk[0] = (int)pack2(h0, h1);
          pk[1] = (int)pack2(h2, h3);
          *(int2v*)(smem + H1_OFF + c * 512 + bb * 16 + hi * 8) = pk;
        }
      }
    }
  }
  __syncthreads();   // H1 complete

  // ================= Layer 2 (no internal barriers) =================
  {
    f32x16 acc2[4];
#pragma unroll
    for (int ct = 0; ct < 4; ++ct) acc2[ct] = (f32x16)Z16;

#pragma unroll
    for (int rb = 0; rb < 4; ++rb) {
      f32x16 acc = (f32x16)Z16;
#pragma unroll
      for (int ks = 0; ks < 16; ++ks) {
        short8 ha = *(const short8*)(smem + H1_OFF + (rb * 32 + n32) * 512 +
                                     (((ks * 2 + hi) ^ s7)) * 16);
        short8 wfr = *(const short8*)(W2t + (size_t)(w * 32 + n32) * 256 + ks * 16 + hi * 8);
        acc = __builtin_amdgcn_mfma_f32_32x32x16_bf16(ha, wfr, acc, 0, 0, 0);
      }
      f32x4 dv0 = *(const f32x4*)(dinvp + rb * 32 + 0 + hi * 4);
      f32x4 dv1 = *(const f32x4*)(dinvp + rb * 32 + 8 + hi * 4);
      f32x4 dv2 = *(const f32x4*)(dinvp + rb * 32 + 16 + hi * 4);
      f32x4 dv3 = *(const f32x4*)(dinvp + rb * 32 + 24 + hi * 4);
      unsigned pk0l = pack2(acc[0] * dv0[0],  acc[1] * dv0[1]);
      unsigned pk0h = pack2(acc[2] * dv0[2],  acc[3] * dv0[3]);
      unsigned pk1l = pack2(acc[4] * dv1[0],  acc[5] * dv1[1]);
      unsigned pk1h = pack2(acc[6] * dv1[2],  acc[7] * dv1[3]);
      unsigned pk2l = pack2(acc[8] * dv2[0],  acc[9] * dv2[1]);
      unsigned pk2h = pack2(acc[10] * dv2[2], acc[11] * dv2[3]);
      unsigned pk3l = pack2(acc[12] * dv3[0], acc[13] * dv3[1]);
      unsigned pk3h = pack2(acc[14] * dv3[2], acc[15] * dv3[3]);
      unsigned rv0l = (unsigned)__shfl_xor((int)pk0l, 32);
      unsigned rv0h = (unsigned)__shfl_xor((int)pk0h, 32);
      unsigned rv1l = (unsigned)__shfl_xor((int)pk1l, 32);
      unsigned rv1h = (unsigned)__shfl_xor((int)pk1h, 32);
      unsigned rv2l = (unsigned)__shfl_xor((int)pk2l, 32);
      unsigned rv2h = (unsigned)__shfl_xor((int)pk2h, 32);
      unsigned rv3l = (unsigned)__shfl_xor((int)pk3l, 32);
      unsigned rv3h = (unsigned)__shfl_xor((int)pk3h, 32);
      short8 A0 = mk8(hi ? rv1l : pk0l, hi ? rv1h : pk0h,
                      hi ? pk1l : rv0l, hi ? pk1h : rv0h);
      short8 A1 = mk8(hi ? rv3l : pk2l, hi ? rv3h : pk2h,
                      hi ? pk3l : rv2l, hi ? pk3h : rv2h);
#pragma unroll
      for (int ct = 0; ct < 4; ++ct) {
        int c = ct * 32 + n32;
        short8 B0 = *(const short8*)(smem + M_OFF + c * 256 + ((rb * 4 + hi) ^ s7) * 16);
        short8 B1 = *(const short8*)(smem + M_OFF + c * 256 + ((rb * 4 + 2 + hi) ^ s7) * 16);
        acc2[ct] = __builtin_amdgcn_mfma_f32_32x32x16_bf16(A0, B0, acc2[ct], 0, 0, 0);
        acc2[ct] = __builtin_amdgcn_mfma_f32_32x32x16_bf16(A1, B1, acc2[ct], 0, 0, 0);
      }
    }

    // epilogue: h2 -> classifier partial dot (vectorized Wc/b2 reads)
#pragma unroll
    for (int ct = 0; ct < 4; ++ct) {
      int c = ct * 32 + n32;
      if (c < R_) {
        float dv = dvc[ct];
#pragma unroll
        for (int rq = 0; rq < 4; ++rq) {
          const int f0 = w * 32 + rq * 8 + hi * 4;
          f32x4 bv2 = *(const f32x4*)(b2 + f0);
          float h0 = dv * acc2[ct][rq * 4 + 0] + bv2[0]; h0 = h0 > 0.f ? h0 : 0.2f * h0;
          float h1 = dv * acc2[ct][rq * 4 + 1] + bv2[1]; h1 = h1 > 0.f ? h1 : 0.2f * h1;
          float h2 = dv * acc2[ct][rq * 4 + 2] + bv2[2]; h2 = h2 > 0.f ? h2 : 0.2f * h2;
          float h3 = dv * acc2[ct][rq * 4 + 3] + bv2[3]; h3 = h3 > 0.f ? h3 : 0.2f * h3;
          f32x4 wc0 = *(const f32x4*)(Wc + (size_t)c * H_ + f0);
          f32x4 wc1 = *(const f32x4*)(Wc + (size_t)(H_ * R_) + (size_t)c * H_ + f0);
          ps0 += h0 * wc0[0] + h1 * wc0[1] + h2 * wc0[2] + h3 * wc0[3];
          ps1 += h0 * wc1[0] + h1 * wc1[1] + h2 * wc1[2] + h3 * wc1[3];
        }
      }
    }
  }

  // ---- classifier reduction ----
#pragma unroll
  for (int off = 32; off; off >>= 1) {
    ps0 += __shfl_xor(ps0, off, 64);
    ps1 += __shfl_xor(ps1, off, 64);
  }
  float* red = (float*)(smem + RED_OFF);
  if (lane == 0) { red[w * 2] = ps0; red[w * 2 + 1] = ps1; }
  __syncthreads();
  if (tid == 0) {
    float s0 = 0.f, s1 = 0.f;
#pragma unroll
    for (int i = 0; i < 8; ++i) { s0 += red[i * 2]; s1 += red[i * 2 + 1]; }
    out[b * 2 + 0] = s0 + bc[0];
    out[b * 2 + 1] = s1 + bc[1];
  }
}

extern "C" void kernel_launch(void* const* d_in, const int* in_sizes, int n_in,
                              void* d_out, int out_size, void* d_ws, size_t ws_size,
                              hipStream_t stream) {
  const float* mM = (const float*)d_in[0];
  const float* nf = (const float*)d_in[1];
  const float* W1 = (const float*)d_in[2];
  const float* b1 = (const float*)d_in[3];
  const float* W2 = (const float*)d_in[4];
  const float* b2 = (const float*)d_in[5];
  const float* Wc = (const float*)d_in[6];
  const float* bc = (const float*)d_in[7];
  float* out = (float*)d_out;

  short* W1t = (short*)d_ws;            // 32768 bf16
  short* W2t = W1t + 32768;             // 65536 bf16

  wt_setup<<<384, 256, 0, stream>>>(W1, W2, W1t, W2t);

  hipFuncSetAttribute((const void*)gnn_fused,
                      hipFuncAttributeMaxDynamicSharedMemorySize, LDS_SIZE);
  gnn_fused<<<512, 512, LDS_SIZE, stream>>>(mM, nf, b1, b2, Wc, bc, W1t, W2t, out);
}

// Round 17
// 58.693 us; speedup vs baseline: 1.0783x; 1.0783x over previous
//
#include <hip/hip_runtime.h>

#define R_    116
#define DIN_  116
#define H_    256

typedef float  f32x4   __attribute__((ext_vector_type(4)));
typedef float  f32x16  __attribute__((ext_vector_type(16)));
typedef short  short8  __attribute__((ext_vector_type(8)));
typedef int    int4v   __attribute__((ext_vector_type(4)));
typedef int    int2v   __attribute__((ext_vector_type(2)));

// ---- LDS layout (bytes). 16B-block XOR swizzle per row (block ^= row&7).
#define M_OFF    0        // M  [128 c][128 r] bf16 pitch 256B : bb=(r>>3)^(c&7); relu(m^T)+I
#define X_OFF    32768    // X  [128 r][128 k] bf16 pitch 256B : bb=(k>>3)^(r&7); zero-padded
#define H1_OFF   65536    // H1 [128 c][256 f] bf16 pitch 512B : bb=(f>>3)^(c&7); rows>=116 zeroed
#define DINV_OFF 131072   // 128 f32 (persistent)
#define RED_OFF  131584   // 16 f32
#define LDS_SIZE 131712

#define Z16 {0.f,0.f,0.f,0.f,0.f,0.f,0.f,0.f,0.f,0.f,0.f,0.f,0.f,0.f,0.f,0.f}

__device__ __forceinline__ short f2bf(float f) {
  union { float f; unsigned u; } x; x.f = f;
  unsigned r = x.u + 0x7fffu + ((x.u >> 16) & 1u);
  return (short)(r >> 16);
}
__device__ __forceinline__ float bf2f(short s) {
  union { unsigned u; float f; } x;
  x.u = ((unsigned)(unsigned short)s) << 16;
  return x.f;
}
// HW packed f32->bf16 RTNE: identical values to f2bf, 1 instruction per pair.
__device__ __forceinline__ unsigned pack2(float lo, float hi) {
  unsigned r;
  asm("v_cvt_pk_bf16_f32 %0, %1, %2" : "=v"(r) : "v"(lo), "v"(hi));
  return r;
}
__device__ __forceinline__ short8 mk8(unsigned a, unsigned b, unsigned c, unsigned d) {
  int4v t; t[0] = (int)a; t[1] = (int)b; t[2] = (int)c; t[3] = (int)d;
  return __builtin_bit_cast(short8, t);
}

// Pre-transpose weights to bf16 Wt[f][k], zero-padded K (layer 1).
__global__ void __launch_bounds__(256) wt_setup(const float* __restrict__ W1,
                                                const float* __restrict__ W2,
                                                short* __restrict__ W1t,
                                                short* __restrict__ W2t) {
  int idx = blockIdx.x * 256 + threadIdx.x;      // 384 blocks
  if (idx < 32768) {                             // W1t [256][128]
    int f = idx >> 7, k = idx & 127;
    float v = (k < DIN_) ? W1[k * H_ + f] : 0.f;
    W1t[idx] = f2bf(v);
  } else {                                       // W2t [256][256]
    int j = idx - 32768;
    int f = j >> 8, k = j & 255;
    W2t[j] = f2bf(W2[k * H_ + f]);
  }
}

// 8 waves (512 thr), 32x32x16 MFMA. Wave w owns f-tile w*32..w*32+31 for BOTH layers.
// Phase A: D[r-quads][f=n32] = X @ W.  In-register transform (scale by dinv[r],
// pack to bf16, shfl_xor lane^32) builds phase-B A-frags xs[f=n32][r-slice]
// WITHOUT an LDS round-trip or barrier.  Phase B: D2[f-quads][c=n32] += xs @ M^T.
__global__ void __launch_bounds__(512, 2) gnn_fused(
    const float* __restrict__ mM, const float* __restrict__ nf,
    const float* __restrict__ b1, const float* __restrict__ b2,
    const float* __restrict__ Wc, const float* __restrict__ bc,
    const short* __restrict__ W1t, const short* __restrict__ W2t,
    float* __restrict__ out)
{
  extern __shared__ char smem[];
  const int b    = blockIdx.x;
  const int tid  = threadIdx.x;
  const int lane = tid & 63;
  const int w    = tid >> 6;     // 0..7 : f-tile (32 cols, both layers)
  const int n32  = lane & 31;
  const int hi   = lane >> 5;
  const int s7   = n32 & 7;

  // ---- prefetch fill inputs: all 14 loads issued up front (named scalars;
  //      units tid+{0..5}*512 are always < 3364 for tid<512, only +3072 guarded)
  const float* mB = mM + (size_t)b * (R_ * R_);
  const float* xB = nf + (size_t)b * (R_ * DIN_);
  const bool g6 = (tid + 3072) < (R_ * R_) / 4;
  f32x4 m0 = ((const f32x4*)mB)[tid];
  f32x4 x0 = ((const f32x4*)xB)[tid];
  f32x4 m1 = ((const f32x4*)mB)[tid + 512];
  f32x4 x1 = ((const f32x4*)xB)[tid + 512];
  f32x4 m2 = ((const f32x4*)mB)[tid + 1024];
  f32x4 x2 = ((const f32x4*)xB)[tid + 1024];
  f32x4 m3 = ((const f32x4*)mB)[tid + 1536];
  f32x4 x3 = ((const f32x4*)xB)[tid + 1536];
  f32x4 m4 = ((const f32x4*)mB)[tid + 2048];
  f32x4 x4_ = ((const f32x4*)xB)[tid + 2048];
  f32x4 m5 = ((const f32x4*)mB)[tid + 2560];
  f32x4 x5 = ((const f32x4*)xB)[tid + 2560];
  f32x4 m6 = (f32x4){0.f, 0.f, 0.f, 0.f};
  f32x4 x6 = (f32x4){0.f, 0.f, 0.f, 0.f};
  if (g6) {
    m6 = ((const f32x4*)mB)[tid + 3072];
    x6 = ((const f32x4*)xB)[tid + 3072];
  }

  // ---- zero M + X + H1 (128KB: covers all padding incl. H1 rows >= 116) ----
  for (int t = tid; t < 131072 / 16; t += 512)
    ((int4v*)smem)[t] = (int4v){0, 0, 0, 0};
  __syncthreads();

  // ---- fill M (transposed, relu, +1 diag) and X (bf16) from prefetched regs ----
#define PROC_UNIT(T4, V4, X4)                                                   \
  do {                                                                          \
    int i0 = (T4) * 4;                                                          \
    int r = i0 / R_, c0 = i0 - r * R_;          /* c0 % 4 == 0 */               \
    _Pragma("unroll") for (int e = 0; e < 4; ++e) {                             \
      int c = c0 + e;                                                           \
      float v = (V4)[e];                                                        \
      v = v > 0.f ? v : 0.f;                                                    \
      if (r == c) v += 1.f;                                                     \
      int ba = (r >> 3) ^ (c & 7);                                              \
      *(short*)(smem + M_OFF + c * 256 + ba * 16 + (r & 7) * 2) = f2bf(v);      \
    }                                                                           \
    {                                                                           \
      int bx = (c0 >> 3) ^ (r & 7);                                             \
      int2v px;                                                                 \
      px[0] = (int)pack2((X4)[0], (X4)[1]);                                     \
      px[1] = (int)pack2((X4)[2], (X4)[3]);                                     \
      *(int2v*)(smem + X_OFF + r * 256 + bx * 16 + (c0 & 7) * 2) = px;          \
    }                                                                           \
  } while (0)

  PROC_UNIT(tid,        m0, x0);
  PROC_UNIT(tid + 512,  m1, x1);
  PROC_UNIT(tid + 1024, m2, x2);
  PROC_UNIT(tid + 1536, m3, x3);
  PROC_UNIT(tid + 2048, m4, x4_);
  PROC_UNIT(tid + 2560, m5, x5);
  if (g6) PROC_UNIT(tid + 3072, m6, x6);
#undef PROC_UNIT
  __syncthreads();

  // ---- deg/dinv: 4 threads per row -> persistent DINV region ----
  {
    float* dp = (float*)(smem + DINV_OFF);
    int row = tid >> 2, part = tid & 3;
    float s = 0.f;
#pragma unroll
    for (int j = 0; j < 4; ++j) {
      int bb = (part * 4 + j) ^ (row & 7);
      short8 v = *(const short8*)(smem + M_OFF + row * 256 + bb * 16);
#pragma unroll
      for (int e = 0; e < 8; ++e) s += bf2f(v[e]);
    }
    s += __shfl_xor(s, 1);
    s += __shfl_xor(s, 2);
    if (part == 0) dp[row] = (row < R_) ? rsqrtf(s) : 0.f;
  }
  __syncthreads();

  const float* dinvp = (const float*)(smem + DINV_OFF);
  float dvc[4];
#pragma unroll
  for (int ct = 0; ct < 4; ++ct) dvc[ct] = dinvp[ct * 32 + n32];

  float ps0 = 0.f, ps1 = 0.f;

  // ================= Layer 1 (no internal barriers) =================
  {
    short8 w1f[8];
#pragma unroll
    for (int ks = 0; ks < 8; ++ks)
      w1f[ks] = *(const short8*)(W1t + (size_t)(w * 32 + n32) * 128 + ks * 16 + hi * 8);

    f32x16 acc2[4];
#pragma unroll
    for (int ct = 0; ct < 4; ++ct) acc2[ct] = (f32x16)Z16;

#pragma unroll
    for (int rb = 0; rb < 4; ++rb) {
      // phase A: xw tile [32 r x 32 f], D[r-quads][f=n32]
      f32x16 acc = (f32x16)Z16;
#pragma unroll
      for (int ks = 0; ks < 8; ++ks) {
        short8 xa = *(const short8*)(smem + X_OFF + (rb * 32 + n32) * 256 +
                                     (((ks * 2 + hi) ^ s7)) * 16);
        acc = __builtin_amdgcn_mfma_f32_32x32x16_bf16(xa, w1f[ks], acc, 0, 0, 0);
      }
      // in-register: scale by dinv[r], pack bf16, exchange lane^32 -> A-frags
      f32x4 dv0 = *(const f32x4*)(dinvp + rb * 32 + 0 + hi * 4);
      f32x4 dv1 = *(const f32x4*)(dinvp + rb * 32 + 8 + hi * 4);
      f32x4 dv2 = *(const f32x4*)(dinvp + rb * 32 + 16 + hi * 4);
      f32x4 dv3 = *(const f32x4*)(dinvp + rb * 32 + 24 + hi * 4);
      unsigned pk0l = pack2(acc[0] * dv0[0],  acc[1] * dv0[1]);
      unsigned pk0h = pack2(acc[2] * dv0[2],  acc[3] * dv0[3]);
      unsigned pk1l = pack2(acc[4] * dv1[0],  acc[5] * dv1[1]);
      unsigned pk1h = pack2(acc[6] * dv1[2],  acc[7] * dv1[3]);
      unsigned pk2l = pack2(acc[8] * dv2[0],  acc[9] * dv2[1]);
      unsigned pk2h = pack2(acc[10] * dv2[2], acc[11] * dv2[3]);
      unsigned pk3l = pack2(acc[12] * dv3[0], acc[13] * dv3[1]);
      unsigned pk3h = pack2(acc[14] * dv3[2], acc[15] * dv3[3]);
      unsigned rv0l = (unsigned)__shfl_xor((int)pk0l, 32);
      unsigned rv0h = (unsigned)__shfl_xor((int)pk0h, 32);
      unsigned rv1l = (unsigned)__shfl_xor((int)pk1l, 32);
      unsigned rv1h = (unsigned)__shfl_xor((int)pk1h, 32);
      unsigned rv2l = (unsigned)__shfl_xor((int)pk2l, 32);
      unsigned rv2h = (unsigned)__shfl_xor((int)pk2h, 32);
      unsigned rv3l = (unsigned)__shfl_xor((int)pk3l, 32);
      unsigned rv3h = (unsigned)__shfl_xor((int)pk3h, 32);
      short8 A0 = mk8(hi ? rv1l : pk0l, hi ? rv1h : pk0h,
                      hi ? pk1l : rv0l, hi ? pk1h : rv0h);
      short8 A1 = mk8(hi ? rv3l : pk2l, hi ? rv3h : pk2h,
                      hi ? pk3l : rv2l, hi ? pk3h : rv2h);
      // phase B: D2[f-quads][c=n32] += xs @ M^T (K = this rb's 32 r)
#pragma unroll
      for (int ct = 0; ct < 4; ++ct) {
        int c = ct * 32 + n32;
        short8 B0 = *(const short8*)(smem + M_OFF + c * 256 + ((rb * 4 + hi) ^ s7) * 16);
        short8 B1 = *(const short8*)(smem + M_OFF + c * 256 + ((rb * 4 + 2 + hi) ^ s7) * 16);
        acc2[ct] = __builtin_amdgcn_mfma_f32_32x32x16_bf16(A0, B0, acc2[ct], 0, 0, 0);
        acc2[ct] = __builtin_amdgcn_mfma_f32_32x32x16_bf16(A1, B1, acc2[ct], 0, 0, 0);
      }
    }

    // epilogue: h1 = leaky(dinv[c]*agg + b1[f]) -> H1[c][f]
    f32x4 bv[4];
#pragma unroll
    for (int rq = 0; rq < 4; ++rq)
      bv[rq] = *(const f32x4*)(b1 + w * 32 + rq * 8 + hi * 4);
#pragma unroll
    for (int ct = 0; ct < 4; ++ct) {
      int c = ct * 32 + n32;
      if (c < R_) {
        float dv = dvc[ct];
#pragma unroll
        for (int rq = 0; rq < 4; ++rq) {
          const int f0 = w * 32 + rq * 8 + hi * 4;
          float h0 = dv * acc2[ct][rq * 4 + 0] + bv[rq][0]; h0 = h0 > 0.f ? h0 : 0.2f * h0;
          float h1 = dv * acc2[ct][rq * 4 + 1] + bv[rq][1]; h1 = h1 > 0.f ? h1 : 0.2f * h1;
          float h2 = dv * acc2[ct][rq * 4 + 2] + bv[rq][2]; h2 = h2 > 0.f ? h2 : 0.2f * h2;
          float h3 = dv * acc2[ct][rq * 4 + 3] + bv[rq][3]; h3 = h3 > 0.f ? h3 : 0.2f * h3;
          int bb = (w * 4 + rq) ^ s7;            // (f0>>3)^(c&7), c&7==s7
          int2v pk;
          pk[0] = (int)pack2(h0, h1);
          pk[1] = (int)pack2(h2, h3);
          *(int2v*)(smem + H1_OFF + c * 512 + bb * 16 + hi * 8) = pk;
        }
      }
    }
  }
  __syncthreads();   // H1 complete

  // ================= Layer 2 (no internal barriers) =================
  {
    f32x16 acc2[4];
#pragma unroll
    for (int ct = 0; ct < 4; ++ct) acc2[ct] = (f32x16)Z16;

#pragma unroll
    for (int rb = 0; rb < 4; ++rb) {
      f32x16 acc = (f32x16)Z16;
#pragma unroll
      for (int ks = 0; ks < 16; ++ks) {
        short8 ha = *(const short8*)(smem + H1_OFF + (rb * 32 + n32) * 512 +
                                     (((ks * 2 + hi) ^ s7)) * 16);
        short8 wfr = *(const short8*)(W2t + (size_t)(w * 32 + n32) * 256 + ks * 16 + hi * 8);
        acc = __builtin_amdgcn_mfma_f32_32x32x16_bf16(ha, wfr, acc, 0, 0, 0);
      }
      f32x4 dv0 = *(const f32x4*)(dinvp + rb * 32 + 0 + hi * 4);
      f32x4 dv1 = *(const f32x4*)(dinvp + rb * 32 + 8 + hi * 4);
      f32x4 dv2 = *(const f32x4*)(dinvp + rb * 32 + 16 + hi * 4);
      f32x4 dv3 = *(const f32x4*)(dinvp + rb * 32 + 24 + hi * 4);
      unsigned pk0l = pack2(acc[0] * dv0[0],  acc[1] * dv0[1]);
      unsigned pk0h = pack2(acc[2] * dv0[2],  acc[3] * dv0[3]);
      unsigned pk1l = pack2(acc[4] * dv1[0],  acc[5] * dv1[1]);
      unsigned pk1h = pack2(acc[6] * dv1[2],  acc[7] * dv1[3]);
      unsigned pk2l = pack2(acc[8] * dv2[0],  acc[9] * dv2[1]);
      unsigned pk2h = pack2(acc[10] * dv2[2], acc[11] * dv2[3]);
      unsigned pk3l = pack2(acc[12] * dv3[0], acc[13] * dv3[1]);
      unsigned pk3h = pack2(acc[14] * dv3[2], acc[15] * dv3[3]);
      unsigned rv0l = (unsigned)__shfl_xor((int)pk0l, 32);
      unsigned rv0h = (unsigned)__shfl_xor((int)pk0h, 32);
      unsigned rv1l = (unsigned)__shfl_xor((int)pk1l, 32);
      unsigned rv1h = (unsigned)__shfl_xor((int)pk1h, 32);
      unsigned rv2l = (unsigned)__shfl_xor((int)pk2l, 32);
      unsigned rv2h = (unsigned)__shfl_xor((int)pk2h, 32);
      unsigned rv3l = (unsigned)__shfl_xor((int)pk3l, 32);
      unsigned rv3h = (unsigned)__shfl_xor((int)pk3h, 32);
      short8 A0 = mk8(hi ? rv1l : pk0l, hi ? rv1h : pk0h,
                      hi ? pk1l : rv0l, hi ? pk1h : rv0h);
      short8 A1 = mk8(hi ? rv3l : pk2l, hi ? rv3h : pk2h,
                      hi ? pk3l : rv2l, hi ? pk3h : rv2h);
#pragma unroll
      for (int ct = 0; ct < 4; ++ct) {
        int c = ct * 32 + n32;
        short8 B0 = *(const short8*)(smem + M_OFF + c * 256 + ((rb * 4 + hi) ^ s7) * 16);
        short8 B1 = *(const short8*)(smem + M_OFF + c * 256 + ((rb * 4 + 2 + hi) ^ s7) * 16);
        acc2[ct] = __builtin_amdgcn_mfma_f32_32x32x16_bf16(A0, B0, acc2[ct], 0, 0, 0);
        acc2[ct] = __builtin_amdgcn_mfma_f32_32x32x16_bf16(A1, B1, acc2[ct], 0, 0, 0);
      }
    }

    // epilogue: h2 -> classifier partial dot (vectorized Wc/b2 reads)
#pragma unroll
    for (int ct = 0; ct < 4; ++ct) {
      int c = ct * 32 + n32;
      if (c < R_) {
        float dv = dvc[ct];
#pragma unroll
        for (int rq = 0; rq < 4; ++rq) {
          const int f0 = w * 32 + rq * 8 + hi * 4;
          f32x4 bv2 = *(const f32x4*)(b2 + f0);
          float h0 = dv * acc2[ct][rq * 4 + 0] + bv2[0]; h0 = h0 > 0.f ? h0 : 0.2f * h0;
          float h1 = dv * acc2[ct][rq * 4 + 1] + bv2[1]; h1 = h1 > 0.f ? h1 : 0.2f * h1;
          float h2 = dv * acc2[ct][rq * 4 + 2] + bv2[2]; h2 = h2 > 0.f ? h2 : 0.2f * h2;
          float h3 = dv * acc2[ct][rq * 4 + 3] + bv2[3]; h3 = h3 > 0.f ? h3 : 0.2f * h3;
          f32x4 wc0 = *(const f32x4*)(Wc + (size_t)c * H_ + f0);
          f32x4 wc1 = *(const f32x4*)(Wc + (size_t)(H_ * R_) + (size_t)c * H_ + f0);
          ps0 += h0 * wc0[0] + h1 * wc0[1] + h2 * wc0[2] + h3 * wc0[3];
          ps1 += h0 * wc1[0] + h1 * wc1[1] + h2 * wc1[2] + h3 * wc1[3];
        }
      }
    }
  }

  // ---- classifier reduction ----
#pragma unroll
  for (int off = 32; off; off >>= 1) {
    ps0 += __shfl_xor(ps0, off, 64);
    ps1 += __shfl_xor(ps1, off, 64);
  }
  float* red = (float*)(smem + RED_OFF);
  if (lane == 0) { red[w * 2] = ps0; red[w * 2 + 1] = ps1; }
  __syncthreads();
  if (tid == 0) {
    float s0 = 0.f, s1 = 0.f;
#pragma unroll
    for (int i = 0; i < 8; ++i) { s0 += red[i * 2]; s1 += red[i * 2 + 1]; }
    out[b * 2 + 0] = s0 + bc[0];
    out[b * 2 + 1] = s1 + bc[1];
  }
}

extern "C" void kernel_launch(void* const* d_in, const int* in_sizes, int n_in,
                              void* d_out, int out_size, void* d_ws, size_t ws_size,
                              hipStream_t stream) {
  const float* mM = (const float*)d_in[0];
  const float* nf = (const float*)d_in[1];
  const float* W1 = (const float*)d_in[2];
  const float* b1 = (const float*)d_in[3];
  const float* W2 = (const float*)d_in[4];
  const float* b2 = (const float*)d_in[5];
  const float* Wc = (const float*)d_in[6];
  const float* bc = (const float*)d_in[7];
  float* out = (float*)d_out;

  short* W1t = (short*)d_ws;            // 32768 bf16
  short* W2t = W1t + 32768;             // 65536 bf16

  wt_setup<<<384, 256, 0, stream>>>(W1, W2, W1t, W2t);

  hipFuncSetAttribute((const void*)gnn_fused,
                      hipFuncAttributeMaxDynamicSharedMemorySize, LDS_SIZE);
  gnn_fused<<<512, 512, LDS_SIZE, stream>>>(mM, nf, b1, b2, Wc, bc, W1t, W2t, out);
}

// Round 19
// 55.918 us; speedup vs baseline: 1.1318x; 1.0496x over previous
//
#include <hip/hip_runtime.h>

#define R_    116
#define DIN_  116
#define H_    256

typedef float  f32x4   __attribute__((ext_vector_type(4)));
typedef float  f32x16  __attribute__((ext_vector_type(16)));
typedef short  short8  __attribute__((ext_vector_type(8)));
typedef int    int4v   __attribute__((ext_vector_type(4)));
typedef int    int2v   __attribute__((ext_vector_type(2)));

// ---- LDS layout (bytes). 16B-block XOR swizzle per row (block ^= row&7).
#define M_OFF    0        // M  [128 c][128 r] bf16 pitch 256B : bb=(r>>3)^(c&7); relu(m^T)+I
#define X_OFF    32768    // X  [128 r][128 k] bf16 pitch 256B : bb=(k>>3)^(r&7); zero-padded
#define H1_OFF   65536    // H1 [128 c][256 f] bf16 pitch 512B : bb=(f>>3)^(c&7); rows>=116 zeroed
#define DINV_OFF 131072   // 128 f32 (persistent)
#define RED_OFF  131584   // 16 f32
#define LDS_SIZE 131712

#define Z16 {0.f,0.f,0.f,0.f,0.f,0.f,0.f,0.f,0.f,0.f,0.f,0.f,0.f,0.f,0.f,0.f}

__device__ __forceinline__ short f2bf(float f) {
  union { float f; unsigned u; } x; x.f = f;
  unsigned r = x.u + 0x7fffu + ((x.u >> 16) & 1u);
  return (short)(r >> 16);
}
__device__ __forceinline__ float bf2f(short s) {
  union { unsigned u; float f; } x;
  x.u = ((unsigned)(unsigned short)s) << 16;
  return x.f;
}
// HW packed f32->bf16 RTNE: identical values to f2bf, 1 instruction per pair.
__device__ __forceinline__ unsigned pack2(float lo, float hi) {
  unsigned r;
  asm("v_cvt_pk_bf16_f32 %0, %1, %2" : "=v"(r) : "v"(lo), "v"(hi));
  return r;
}
__device__ __forceinline__ short8 mk8(unsigned a, unsigned b, unsigned c, unsigned d) {
  int4v t; t[0] = (int)a; t[1] = (int)b; t[2] = (int)c; t[3] = (int)d;
  return __builtin_bit_cast(short8, t);
}

// Pre-transpose weights to bf16 Wt[f][k], zero-padded K (layer 1).
__global__ void __launch_bounds__(256) wt_setup(const float* __restrict__ W1,
                                                const float* __restrict__ W2,
                                                short* __restrict__ W1t,
                                                short* __restrict__ W2t) {
  int idx = blockIdx.x * 256 + threadIdx.x;      // 384 blocks
  if (idx < 32768) {                             // W1t [256][128]
    int f = idx >> 7, k = idx & 127;
    float v = (k < DIN_) ? W1[k * H_ + f] : 0.f;
    W1t[idx] = f2bf(v);
  } else {                                       // W2t [256][256]
    int j = idx - 32768;
    int f = j >> 8, k = j & 255;
    W2t[j] = f2bf(W2[k * H_ + f]);
  }
}

// 8 waves (512 thr), 32x32x16 MFMA. Wave w owns f-tile w*32..w*32+31 for BOTH layers.
// Phase A: D[r-quads][f=n32] = X @ W.  In-register transform (scale by dinv[r],
// pack to bf16, shfl_xor lane^32) builds phase-B A-frags xs[f=n32][r-slice]
// WITHOUT an LDS round-trip or barrier.  Phase B: D2[f-quads][c=n32] += xs @ M^T.
// launch_bounds (512,1): dynamic LDS caps us at 1 block/CU anyway; declaring
// min 1 wave/EU lifts the allocator's 128-VGPR self-cap (was spilling ~2MB).
__global__ void __launch_bounds__(512, 1) gnn_fused(
    const float* __restrict__ mM, const float* __restrict__ nf,
    const float* __restrict__ b1, const float* __restrict__ b2,
    const float* __restrict__ Wc, const float* __restrict__ bc,
    const short* __restrict__ W1t, const short* __restrict__ W2t,
    float* __restrict__ out)
{
  extern __shared__ char smem[];
  const int b    = blockIdx.x;
  const int tid  = threadIdx.x;
  const int lane = tid & 63;
  const int w    = tid >> 6;     // 0..7 : f-tile (32 cols, both layers)
  const int n32  = lane & 31;
  const int hi   = lane >> 5;
  const int s7   = n32 & 7;

  // ---- zero M + X + H1 (128KB: covers all padding incl. H1 rows >= 116) ----
  for (int t = tid; t < 131072 / 16; t += 512)
    ((int4v*)smem)[t] = (int4v){0, 0, 0, 0};
  __syncthreads();

  // ---- fill M (transposed, relu, +1 diag) and X (bf16), coalesced f32x4 reads ----
  {
    const float* mB = mM + (size_t)b * (R_ * R_);
    const float* xB = nf + (size_t)b * (R_ * DIN_);
    for (int t4 = tid; t4 < (R_ * R_) / 4; t4 += 512) {
      f32x4 v4 = ((const f32x4*)mB)[t4];
      f32x4 x4 = ((const f32x4*)xB)[t4];
      int i0 = t4 * 4;
      int r = i0 / R_, c0 = i0 - r * R_;          // c0 % 4 == 0 (116 % 4 == 0)
#pragma unroll
      for (int e = 0; e < 4; ++e) {               // M: rows differ -> scalar stores
        int c = c0 + e;
        float v = v4[e];
        v = v > 0.f ? v : 0.f;
        if (r == c) v += 1.f;
        int ba = (r >> 3) ^ (c & 7);
        *(short*)(smem + M_OFF + c * 256 + ba * 16 + (r & 7) * 2) = f2bf(v);
      }
      {                                           // X: same row -> one 8B store
        int bx = (c0 >> 3) ^ (r & 7);
        int2v px;
        px[0] = (int)pack2(x4[0], x4[1]);
        px[1] = (int)pack2(x4[2], x4[3]);
        *(int2v*)(smem + X_OFF + r * 256 + bx * 16 + (c0 & 7) * 2) = px;
      }
    }
  }
  __syncthreads();

  // ---- deg/dinv: 4 threads per row -> persistent DINV region ----
  {
    float* dp = (float*)(smem + DINV_OFF);
    int row = tid >> 2, part = tid & 3;
    float s = 0.f;
#pragma unroll
    for (int j = 0; j < 4; ++j) {
      int bb = (part * 4 + j) ^ (row & 7);
      short8 v = *(const short8*)(smem + M_OFF + row * 256 + bb * 16);
#pragma unroll
      for (int e = 0; e < 8; ++e) s += bf2f(v[e]);
    }
    s += __shfl_xor(s, 1);
    s += __shfl_xor(s, 2);
    if (part == 0) dp[row] = (row < R_) ? rsqrtf(s) : 0.f;
  }
  __syncthreads();

  const float* dinvp = (const float*)(smem + DINV_OFF);
  float dvc[4];
#pragma unroll
  for (int ct = 0; ct < 4; ++ct) dvc[ct] = dinvp[ct * 32 + n32];

  float ps0 = 0.f, ps1 = 0.f;

  // ================= Layer 1 (no internal barriers) =================
  {
    short8 w1f[8];
#pragma unroll
    for (int ks = 0; ks < 8; ++ks)
      w1f[ks] = *(const short8*)(W1t + (size_t)(w * 32 + n32) * 128 + ks * 16 + hi * 8);

    f32x16 acc2[4];
#pragma unroll
    for (int ct = 0; ct < 4; ++ct) acc2[ct] = (f32x16)Z16;

#pragma unroll
    for (int rb = 0; rb < 4; ++rb) {
      // phase A: xw tile [32 r x 32 f], D[r-quads][f=n32]
      f32x16 acc = (f32x16)Z16;
#pragma unroll
      for (int ks = 0; ks < 8; ++ks) {
        short8 xa = *(const short8*)(smem + X_OFF + (rb * 32 + n32) * 256 +
                                     (((ks * 2 + hi) ^ s7)) * 16);
        acc = __builtin_amdgcn_mfma_f32_32x32x16_bf16(xa, w1f[ks], acc, 0, 0, 0);
      }
      // in-register: scale by dinv[r], pack bf16, exchange lane^32 -> A-frags
      f32x4 dv0 = *(const f32x4*)(dinvp + rb * 32 + 0 + hi * 4);
      f32x4 dv1 = *(const f32x4*)(dinvp + rb * 32 + 8 + hi * 4);
      f32x4 dv2 = *(const f32x4*)(dinvp + rb * 32 + 16 + hi * 4);
      f32x4 dv3 = *(const f32x4*)(dinvp + rb * 32 + 24 + hi * 4);
      unsigned pk0l = pack2(acc[0] * dv0[0],  acc[1] * dv0[1]);
      unsigned pk0h = pack2(acc[2] * dv0[2],  acc[3] * dv0[3]);
      unsigned pk1l = pack2(acc[4] * dv1[0],  acc[5] * dv1[1]);
      unsigned pk1h = pack2(acc[6] * dv1[2],  acc[7] * dv1[3]);
      unsigned pk2l = pack2(acc[8] * dv2[0],  acc[9] * dv2[1]);
      unsigned pk2h = pack2(acc[10] * dv2[2], acc[11] * dv2[3]);
      unsigned pk3l = pack2(acc[12] * dv3[0], acc[13] * dv3[1]);
      unsigned pk3h = pack2(acc[14] * dv3[2], acc[15] * dv3[3]);
      unsigned rv0l = (unsigned)__shfl_xor((int)pk0l, 32);
      unsigned rv0h = (unsigned)__shfl_xor((int)pk0h, 32);
      unsigned rv1l = (unsigned)__shfl_xor((int)pk1l, 32);
      unsigned rv1h = (unsigned)__shfl_xor((int)pk1h, 32);
      unsigned rv2l = (unsigned)__shfl_xor((int)pk2l, 32);
      unsigned rv2h = (unsigned)__shfl_xor((int)pk2h, 32);
      unsigned rv3l = (unsigned)__shfl_xor((int)pk3l, 32);
      unsigned rv3h = (unsigned)__shfl_xor((int)pk3h, 32);
      short8 A0 = mk8(hi ? rv1l : pk0l, hi ? rv1h : pk0h,
                      hi ? pk1l : rv0l, hi ? pk1h : rv0h);
      short8 A1 = mk8(hi ? rv3l : pk2l, hi ? rv3h : pk2h,
                      hi ? pk3l : rv2l, hi ? pk3h : rv2h);
      // phase B: D2[f-quads][c=n32] += xs @ M^T (K = this rb's 32 r)
#pragma unroll
      for (int ct = 0; ct < 4; ++ct) {
        int c = ct * 32 + n32;
        short8 B0 = *(const short8*)(smem + M_OFF + c * 256 + ((rb * 4 + hi) ^ s7) * 16);
        short8 B1 = *(const short8*)(smem + M_OFF + c * 256 + ((rb * 4 + 2 + hi) ^ s7) * 16);
        acc2[ct] = __builtin_amdgcn_mfma_f32_32x32x16_bf16(A0, B0, acc2[ct], 0, 0, 0);
        acc2[ct] = __builtin_amdgcn_mfma_f32_32x32x16_bf16(A1, B1, acc2[ct], 0, 0, 0);
      }
    }

    // epilogue: h1 = leaky(dinv[c]*agg + b1[f]) -> H1[c][f]
    f32x4 bv[4];
#pragma unroll
    for (int rq = 0; rq < 4; ++rq)
      bv[rq] = *(const f32x4*)(b1 + w * 32 + rq * 8 + hi * 4);
#pragma unroll
    for (int ct = 0; ct < 4; ++ct) {
      int c = ct * 32 + n32;
      if (c < R_) {
        float dv = dvc[ct];
#pragma unroll
        for (int rq = 0; rq < 4; ++rq) {
          const int f0 = w * 32 + rq * 8 + hi * 4;
          float h0 = dv * acc2[ct][rq * 4 + 0] + bv[rq][0]; h0 = h0 > 0.f ? h0 : 0.2f * h0;
          float h1 = dv * acc2[ct][rq * 4 + 1] + bv[rq][1]; h1 = h1 > 0.f ? h1 : 0.2f * h1;
          float h2 = dv * acc2[ct][rq * 4 + 2] + bv[rq][2]; h2 = h2 > 0.f ? h2 : 0.2f * h2;
          float h3 = dv * acc2[ct][rq * 4 + 3] + bv[rq][3]; h3 = h3 > 0.f ? h3 : 0.2f * h3;
          int bb = (w * 4 + rq) ^ s7;            // (f0>>3)^(c&7), c&7==s7
          int2v pk;
          pk[0] = (int)pack2(h0, h1);
          pk[1] = (int)pack2(h2, h3);
          *(int2v*)(smem + H1_OFF + c * 512 + bb * 16 + hi * 8) = pk;
        }
      }
    }
  }
  __syncthreads();   // H1 complete

  // ================= Layer 2 (no internal barriers) =================
  {
    f32x16 acc2[4];
#pragma unroll
    for (int ct = 0; ct < 4; ++ct) acc2[ct] = (f32x16)Z16;

#pragma unroll
    for (int rb = 0; rb < 4; ++rb) {
      f32x16 acc = (f32x16)Z16;
#pragma unroll
      for (int ks = 0; ks < 16; ++ks) {
        short8 ha = *(const short8*)(smem + H1_OFF + (rb * 32 + n32) * 512 +
                                     (((ks * 2 + hi) ^ s7)) * 16);
        short8 wfr = *(const short8*)(W2t + (size_t)(w * 32 + n32) * 256 + ks * 16 + hi * 8);
        acc = __builtin_amdgcn_mfma_f32_32x32x16_bf16(ha, wfr, acc, 0, 0, 0);
      }
      f32x4 dv0 = *(const f32x4*)(dinvp + rb * 32 + 0 + hi * 4);
      f32x4 dv1 = *(const f32x4*)(dinvp + rb * 32 + 8 + hi * 4);
      f32x4 dv2 = *(const f32x4*)(dinvp + rb * 32 + 16 + hi * 4);
      f32x4 dv3 = *(const f32x4*)(dinvp + rb * 32 + 24 + hi * 4);
      unsigned pk0l = pack2(acc[0] * dv0[0],  acc[1] * dv0[1]);
      unsigned pk0h = pack2(acc[2] * dv0[2],  acc[3] * dv0[3]);
      unsigned pk1l = pack2(acc[4] * dv1[0],  acc[5] * dv1[1]);
      unsigned pk1h = pack2(acc[6] * dv1[2],  acc[7] * dv1[3]);
      unsigned pk2l = pack2(acc[8] * dv2[0],  acc[9] * dv2[1]);
      unsigned pk2h = pack2(acc[10] * dv2[2], acc[11] * dv2[3]);
      unsigned pk3l = pack2(acc[12] * dv3[0], acc[13] * dv3[1]);
      unsigned pk3h = pack2(acc[14] * dv3[2], acc[15] * dv3[3]);
      unsigned rv0l = (unsigned)__shfl_xor((int)pk0l, 32);
      unsigned rv0h = (unsigned)__shfl_xor((int)pk0h, 32);
      unsigned rv1l = (unsigned)__shfl_xor((int)pk1l, 32);
      unsigned rv1h = (unsigned)__shfl_xor((int)pk1h, 32);
      unsigned rv2l = (unsigned)__shfl_xor((int)pk2l, 32);
      unsigned rv2h = (unsigned)__shfl_xor((int)pk2h, 32);
      unsigned rv3l = (unsigned)__shfl_xor((int)pk3l, 32);
      unsigned rv3h = (unsigned)__shfl_xor((int)pk3h, 32);
      short8 A0 = mk8(hi ? rv1l : pk0l, hi ? rv1h : pk0h,
                      hi ? pk1l : rv0l, hi ? pk1h : rv0h);
      short8 A1 = mk8(hi ? rv3l : pk2l, hi ? rv3h : pk2h,
                      hi ? pk3l : rv2l, hi ? pk3h : rv2h);
#pragma unroll
      for (int ct = 0; ct < 4; ++ct) {
        int c = ct * 32 + n32;
        short8 B0 = *(const short8*)(smem + M_OFF + c * 256 + ((rb * 4 + hi) ^ s7) * 16);
        short8 B1 = *(const short8*)(smem + M_OFF + c * 256 + ((rb * 4 + 2 + hi) ^ s7) * 16);
        acc2[ct] = __builtin_amdgcn_mfma_f32_32x32x16_bf16(A0, B0, acc2[ct], 0, 0, 0);
        acc2[ct] = __builtin_amdgcn_mfma_f32_32x32x16_bf16(A1, B1, acc2[ct], 0, 0, 0);
      }
    }

    // epilogue: h2 -> classifier partial dot (vectorized Wc/b2 reads)
#pragma unroll
    for (int ct = 0; ct < 4; ++ct) {
      int c = ct * 32 + n32;
      if (c < R_) {
        float dv = dvc[ct];
#pragma unroll
        for (int rq = 0; rq < 4; ++rq) {
          const int f0 = w * 32 + rq * 8 + hi * 4;
          f32x4 bv2 = *(const f32x4*)(b2 + f0);
          float h0 = dv * acc2[ct][rq * 4 + 0] + bv2[0]; h0 = h0 > 0.f ? h0 : 0.2f * h0;
          float h1 = dv * acc2[ct][rq * 4 + 1] + bv2[1]; h1 = h1 > 0.f ? h1 : 0.2f * h1;
          float h2 = dv * acc2[ct][rq * 4 + 2] + bv2[2]; h2 = h2 > 0.f ? h2 : 0.2f * h2;
          float h3 = dv * acc2[ct][rq * 4 + 3] + bv2[3]; h3 = h3 > 0.f ? h3 : 0.2f * h3;
          f32x4 wc0 = *(const f32x4*)(Wc + (size_t)c * H_ + f0);
          f32x4 wc1 = *(const f32x4*)(Wc + (size_t)(H_ * R_) + (size_t)c * H_ + f0);
          ps0 += h0 * wc0[0] + h1 * wc0[1] + h2 * wc0[2] + h3 * wc0[3];
          ps1 += h0 * wc1[0] + h1 * wc1[1] + h2 * wc1[2] + h3 * wc1[3];
        }
      }
    }
  }

  // ---- classifier reduction ----
#pragma unroll
  for (int off = 32; off; off >>= 1) {
    ps0 += __shfl_xor(ps0, off, 64);
    ps1 += __shfl_xor(ps1, off, 64);
  }
  float* red = (float*)(smem + RED_OFF);
  if (lane == 0) { red[w * 2] = ps0; red[w * 2 + 1] = ps1; }
  __syncthreads();
  if (tid == 0) {
    float s0 = 0.f, s1 = 0.f;
#pragma unroll
    for (int i = 0; i < 8; ++i) { s0 += red[i * 2]; s1 += red[i * 2 + 1]; }
    out[b * 2 + 0] = s0 + bc[0];
    out[b * 2 + 1] = s1 + bc[1];
  }
}

extern "C" void kernel_launch(void* const* d_in, const int* in_sizes, int n_in,
                              void* d_out, int out_size, void* d_ws, size_t ws_size,
                              hipStream_t stream) {
  const float* mM = (const float*)d_in[0];
  const float* nf = (const float*)d_in[1];
  const float* W1 = (const float*)d_in[2];
  const float* b1 = (const float*)d_in[3];
  const float* W2 = (const float*)d_in[4];
  const float* b2 = (const float*)d_in[5];
  const float* Wc = (const float*)d_in[6];
  const float* bc = (const float*)d_in[7];
  float* out = (float*)d_out;

  short* W1t = (short*)d_ws;            // 32768 bf16
  short* W2t = W1t + 32768;             // 65536 bf16

  wt_setup<<<384, 256, 0, stream>>>(W1, W2, W1t, W2t);

  hipFuncSetAttribute((const void*)gnn_fused,
                      hipFuncAttributeMaxDynamicSharedMemorySize, LDS_SIZE);
  gnn_fused<<<512, 512, LDS_SIZE, stream>>>(mM, nf, b1, b2, Wc, bc, W1t, W2t, out);
}